// Round 1
// baseline (1127.032 us; speedup 1.0000x reference)
//
#include <hip/hip_runtime.h>
#include <hip/hip_bf16.h>
#include <math.h>

// Problem constants
#define DI   1024
#define EI   8
#define HI   4096
#define NI   4096   // B*T

typedef __bf16 bf16x8 __attribute__((ext_vector_type(8)));
typedef float  f32x4  __attribute__((ext_vector_type(4)));

// ---------- helpers ----------
__device__ __forceinline__ unsigned short f2bf(float f) {
  union { float f; unsigned u; } c; c.f = f;
  unsigned r = c.u + 0x7FFF + ((c.u >> 16) & 1);   // RNE
  return (unsigned short)(r >> 16);
}

// async global->LDS, 16B per lane; lds base must be wave-uniform
__device__ __forceinline__ void async16(const void* g, void* l) {
  __builtin_amdgcn_global_load_lds(
      (const __attribute__((address_space(1))) void*)g,
      (__attribute__((address_space(3))) void*)l, 16, 0, 0);
}

// ---------- kernel 1: fused LayerNorm + router ----------
__global__ __launch_bounds__(256) void ln_router_k(
    const float* __restrict__ x, const float* __restrict__ gamma,
    const float* __restrict__ beta, const float* __restrict__ gw,
    unsigned short* __restrict__ xnbf, float* __restrict__ probs_out,
    int* __restrict__ counts, float* __restrict__ psum,
    int* __restrict__ tok_list, float* __restrict__ gate_list)
{
  const int n = blockIdx.x, t = threadIdx.x;
  const int lane = t & 63, wid = t >> 6;
  __shared__ float sbuf[4], qbuf[4], red[4][8], sh[2];

  const float4 v = ((const float4*)(x + (size_t)n * DI))[t];
  float s = v.x + v.y + v.z + v.w;
  float q = v.x * v.x + v.y * v.y + v.z * v.z + v.w * v.w;
  #pragma unroll
  for (int off = 32; off > 0; off >>= 1) {
    s += __shfl_down(s, off);
    q += __shfl_down(q, off);
  }
  if (lane == 0) { sbuf[wid] = s; qbuf[wid] = q; }
  __syncthreads();
  if (t == 0) {
    float S = sbuf[0] + sbuf[1] + sbuf[2] + sbuf[3];
    float Q = qbuf[0] + qbuf[1] + qbuf[2] + qbuf[3];
    float mu = S / (float)DI;
    float var = Q / (float)DI - mu * mu;
    sh[0] = mu; sh[1] = rsqrtf(var + 1e-5f);
  }
  __syncthreads();
  const float mu = sh[0], rs = sh[1];
  const float4 g4 = ((const float4*)gamma)[t];
  const float4 b4 = ((const float4*)beta)[t];
  float xl[4];
  xl[0] = (v.x - mu) * rs * g4.x + b4.x;
  xl[1] = (v.y - mu) * rs * g4.y + b4.y;
  xl[2] = (v.z - mu) * rs * g4.z + b4.z;
  xl[3] = (v.w - mu) * rs * g4.w + b4.w;
  ushort4 o;
  o.x = f2bf(xl[0]); o.y = f2bf(xl[1]); o.z = f2bf(xl[2]); o.w = f2bf(xl[3]);
  ((ushort4*)(xnbf + (size_t)n * DI))[t] = o;

  // router logits (fp32 — top-k selection must be stable)
  float p[8];
  #pragma unroll
  for (int e = 0; e < 8; e++) p[e] = 0.f;
  const float* grow = gw + (size_t)(4 * t) * EI;
  #pragma unroll
  for (int j = 0; j < 4; j++)
    #pragma unroll
    for (int e = 0; e < 8; e++) p[e] += xl[j] * grow[j * EI + e];
  #pragma unroll
  for (int e = 0; e < 8; e++) {
    float ve = p[e];
    #pragma unroll
    for (int off = 32; off > 0; off >>= 1) ve += __shfl_down(ve, off);
    if (lane == 0) red[wid][e] = ve;
  }
  __syncthreads();
  if (t == 0) {
    float l[8], pm = -1e30f;
    #pragma unroll
    for (int e = 0; e < 8; e++) {
      l[e] = red[0][e] + red[1][e] + red[2][e] + red[3][e];
      pm = fmaxf(pm, l[e]);
    }
    float pr[8], ps = 0.f;
    #pragma unroll
    for (int e = 0; e < 8; e++) { pr[e] = expf(l[e] - pm); ps += pr[e]; }
    const float inv = 1.0f / ps;
    #pragma unroll
    for (int e = 0; e < 8; e++) {
      pr[e] *= inv;
      probs_out[(size_t)n * EI + e] = pr[e];
      atomicAdd(&psum[e], pr[e]);
    }
    // top-2, ties -> lowest index (matches lax.top_k)
    int i0 = 0; float m0 = pr[0];
    #pragma unroll
    for (int e = 1; e < 8; e++) if (pr[e] > m0) { m0 = pr[e]; i0 = e; }
    int i1 = -1; float m1 = -1e30f;
    #pragma unroll
    for (int e = 0; e < 8; e++) if (e != i0 && pr[e] > m1) { m1 = pr[e]; i1 = e; }
    const float ssum = m0 + m1 + 1e-8f;
    const float g0 = m0 / ssum, g1 = m1 / ssum;
    int p0 = atomicAdd(&counts[i0], 1);
    tok_list[i0 * NI + p0] = n; gate_list[i0 * NI + p0] = g0;
    int p1 = atomicAdd(&counts[i1], 1);
    tok_list[i1 * NI + p1] = n; gate_list[i1 * NI + p1] = g1;
  }
}

// ---------- kernel 2: transpose fp32 (R,C) -> bf16 (C,R), per expert in z ----------
__global__ __launch_bounds__(256) void transpose_cvt_k(
    const float* __restrict__ in, unsigned short* __restrict__ out, int R, int C)
{
  __shared__ float tile[64][65];
  const size_t eoff = (size_t)blockIdx.z * (size_t)R * (size_t)C;
  const int c0 = blockIdx.x * 64, r0 = blockIdx.y * 64;
  const int tx = threadIdx.x & 63, ty = threadIdx.x >> 6;
  #pragma unroll
  for (int ii = 0; ii < 16; ii++) {
    int i = ty + ii * 4;
    tile[i][tx] = in[eoff + (size_t)(r0 + i) * C + (c0 + tx)];
  }
  __syncthreads();
  #pragma unroll
  for (int ii = 0; ii < 16; ii++) {
    int i = ty + ii * 4;
    out[eoff + (size_t)(c0 + i) * R + (r0 + tx)] = f2bf(tile[tx][i]);
  }
}

// ---------- kernel 3: offsets scan + balance loss ----------
__global__ void scan_bal_k(const int* __restrict__ counts, const float* __restrict__ psum,
                           int* __restrict__ offs, float* __restrict__ out_bal)
{
  int off = 0; float s = 0.f;
  for (int e = 0; e < EI; e++) {
    offs[e] = off; off += counts[e];
    s += (float)counts[e] * psum[e];
  }
  *out_bal = 0.01f * 8.0f * s / ((float)NI * (float)NI);
}

// ---------- kernel 4: residual init out = x ----------
__global__ __launch_bounds__(256) void copy_x_k(const float* __restrict__ x, float* __restrict__ out)
{
  const size_t i = (size_t)blockIdx.x * 256 + threadIdx.x;
  ((float4*)out)[i] = ((const float4*)x)[i];
}

// ---------- kernel 5: grouped GEMM1 + bias + GELU -> h (bf16) ----------
// C[m][n] over m = expert tokens (gathered), n = H cols. K = D.
__global__ __launch_bounds__(256) void ffn1_k(
    const unsigned short* __restrict__ xnbf, const unsigned short* __restrict__ w1t,
    const float* __restrict__ b1, unsigned short* __restrict__ hbuf,
    const int* __restrict__ tok_list, const int* __restrict__ counts,
    const int* __restrict__ offsets)
{
  const int e = blockIdx.z;
  const int cnt = counts[e];
  const int mt = blockIdx.y;
  if (mt * 128 >= cnt) return;
  const int n0 = blockIdx.x * 128;
  const int t = threadIdx.x, lane = t & 63, w = t >> 6;
  const int wm = w & 1, wn = w >> 1;
  __shared__ __align__(16) unsigned short As[128 * 64];  // [m][k], no pad (global_load_lds)
  __shared__ __align__(16) unsigned short Bs[128 * 64];  // [n][k]

  const int sub = lane >> 3, kc = (lane & 7) * 8;
  const unsigned short* baseA[4];
  const unsigned short* baseB[4];
  #pragma unroll
  for (int r = 0; r < 4; r++) {
    int row = (w << 5) + r * 8 + sub;
    int idx = mt * 128 + row; if (idx > cnt - 1) idx = cnt - 1;  // clamp (dup, unused)
    int tok = tok_list[e * NI + idx];
    baseA[r] = xnbf + (size_t)tok * DI + kc;
    baseB[r] = w1t + (size_t)e * HI * DI + (size_t)(n0 + row) * DI + kc;
  }

  f32x4 acc[4][4];
  const f32x4 zz = {0.f, 0.f, 0.f, 0.f};
  #pragma unroll
  for (int i = 0; i < 4; i++)
    #pragma unroll
    for (int j = 0; j < 4; j++) acc[i][j] = zz;

  const int mrow = (wm << 6) + (lane & 15);
  const int nrow = (wn << 6) + (lane & 15);
  const int kq = (lane >> 4) * 8;

  for (int k0 = 0; k0 < DI; k0 += 64) {
    __syncthreads();
    #pragma unroll
    for (int r = 0; r < 4; r++) {
      async16(baseA[r] + k0, &As[((w << 5) + r * 8) * 64]);
      async16(baseB[r] + k0, &Bs[((w << 5) + r * 8) * 64]);
    }
    __syncthreads();
    #pragma unroll
    for (int kk = 0; kk < 2; kk++) {
      bf16x8 af[4], bfr[4];
      #pragma unroll
      for (int mi = 0; mi < 4; mi++)
        af[mi] = *(const bf16x8*)&As[(mrow + mi * 16) * 64 + kk * 32 + kq];
      #pragma unroll
      for (int ni = 0; ni < 4; ni++)
        bfr[ni] = *(const bf16x8*)&Bs[(nrow + ni * 16) * 64 + kk * 32 + kq];
      #pragma unroll
      for (int mi = 0; mi < 4; mi++)
        #pragma unroll
        for (int ni = 0; ni < 4; ni++)
          acc[mi][ni] = __builtin_amdgcn_mfma_f32_16x16x32_bf16(af[mi], bfr[ni], acc[mi][ni], 0, 0, 0);
    }
  }

  // epilogue: bias + exact GELU, store bf16 h (guarded rows)
  const int hb = offsets[e] + mt * 128;
  #pragma unroll
  for (int ni = 0; ni < 4; ni++) {
    const int col = n0 + (wn << 6) + ni * 16 + (lane & 15);
    const float bias = b1[e * HI + col];
    #pragma unroll
    for (int mi = 0; mi < 4; mi++) {
      #pragma unroll
      for (int rg = 0; rg < 4; rg++) {
        const int rowl = (wm << 6) + mi * 16 + ((lane >> 4) << 2) + rg;
        if (mt * 128 + rowl < cnt) {
          float vv = acc[mi][ni][rg] + bias;
          vv = 0.5f * vv * (1.0f + erff(vv * 0.70710678118f));
          hbuf[(size_t)(hb + rowl) * HI + col] = f2bf(vv);
        }
      }
    }
  }
}

// ---------- kernel 6: grouped GEMM2 + bias, gate-scaled scatter-add -> out ----------
// C[m][n] over m = expert rows of h (compact), n = D cols. K = H.
__global__ __launch_bounds__(256) void ffn2_k(
    const unsigned short* __restrict__ hbuf, const unsigned short* __restrict__ w2t,
    const float* __restrict__ b2, float* __restrict__ out,
    const int* __restrict__ tok_list, const float* __restrict__ gate_list,
    const int* __restrict__ counts, const int* __restrict__ offsets)
{
  const int e = blockIdx.z;
  const int cnt = counts[e];
  const int mt = blockIdx.y;
  if (mt * 128 >= cnt) return;
  const int n0 = blockIdx.x * 128;
  const int t = threadIdx.x, lane = t & 63, w = t >> 6;
  const int wm = w & 1, wn = w >> 1;
  __shared__ __align__(16) unsigned short As[128 * 64];
  __shared__ __align__(16) unsigned short Bs[128 * 64];

  const int sub = lane >> 3, kc = (lane & 7) * 8;
  const int hb = offsets[e] + mt * 128;
  const unsigned short* baseA[4];
  const unsigned short* baseB[4];
  #pragma unroll
  for (int r = 0; r < 4; r++) {
    int row = (w << 5) + r * 8 + sub;
    baseA[r] = hbuf + (size_t)(hb + row) * HI + kc;     // h padded by 128 rows
    baseB[r] = w2t + (size_t)e * DI * HI + (size_t)(n0 + row) * HI + kc;
  }

  f32x4 acc[4][4];
  const f32x4 zz = {0.f, 0.f, 0.f, 0.f};
  #pragma unroll
  for (int i = 0; i < 4; i++)
    #pragma unroll
    for (int j = 0; j < 4; j++) acc[i][j] = zz;

  const int mrow = (wm << 6) + (lane & 15);
  const int nrow = (wn << 6) + (lane & 15);
  const int kq = (lane >> 4) * 8;

  for (int k0 = 0; k0 < HI; k0 += 64) {
    __syncthreads();
    #pragma unroll
    for (int r = 0; r < 4; r++) {
      async16(baseA[r] + k0, &As[((w << 5) + r * 8) * 64]);
      async16(baseB[r] + k0, &Bs[((w << 5) + r * 8) * 64]);
    }
    __syncthreads();
    #pragma unroll
    for (int kk = 0; kk < 2; kk++) {
      bf16x8 af[4], bfr[4];
      #pragma unroll
      for (int mi = 0; mi < 4; mi++)
        af[mi] = *(const bf16x8*)&As[(mrow + mi * 16) * 64 + kk * 32 + kq];
      #pragma unroll
      for (int ni = 0; ni < 4; ni++)
        bfr[ni] = *(const bf16x8*)&Bs[(nrow + ni * 16) * 64 + kk * 32 + kq];
      #pragma unroll
      for (int mi = 0; mi < 4; mi++)
        #pragma unroll
        for (int ni = 0; ni < 4; ni++)
          acc[mi][ni] = __builtin_amdgcn_mfma_f32_16x16x32_bf16(af[mi], bfr[ni], acc[mi][ni], 0, 0, 0);
    }
  }

  // epilogue: (acc + b2) * gate, atomic scatter onto residual-initialized out
  float bias[4];
  #pragma unroll
  for (int ni = 0; ni < 4; ni++)
    bias[ni] = b2[e * DI + n0 + (wn << 6) + ni * 16 + (lane & 15)];
  #pragma unroll
  for (int mi = 0; mi < 4; mi++) {
    #pragma unroll
    for (int rg = 0; rg < 4; rg++) {
      const int rowl = (wm << 6) + mi * 16 + ((lane >> 4) << 2) + rg;
      const int gidx = mt * 128 + rowl;
      if (gidx < cnt) {
        const int tok = tok_list[e * NI + gidx];
        const float gte = gate_list[e * NI + gidx];
        float* orow = out + (size_t)tok * DI;
        #pragma unroll
        for (int ni = 0; ni < 4; ni++) {
          const int col = n0 + (wn << 6) + ni * 16 + (lane & 15);
          atomicAdd(orow + col, (acc[mi][ni][rg] + bias[ni]) * gte);
        }
      }
    }
  }
}

// ---------- launch ----------
extern "C" void kernel_launch(void* const* d_in, const int* in_sizes, int n_in,
                              void* d_out, int out_size, void* d_ws, size_t ws_size,
                              hipStream_t stream)
{
  const float* x   = (const float*)d_in[0];
  const float* gam = (const float*)d_in[1];
  const float* bet = (const float*)d_in[2];
  const float* gw  = (const float*)d_in[3];
  const float* w1  = (const float*)d_in[4];
  const float* b1  = (const float*)d_in[5];
  const float* w2  = (const float*)d_in[6];
  const float* b2  = (const float*)d_in[7];
  float* out = (float*)d_out;

  char* ws = (char*)d_ws;
  // ws layout (bytes):
  //   0      counts[8] (int)
  //   64     psum[8] (float)
  //   128    offsets[8] (int)
  //   512    tok_list  E*N int          (131072)
  //   131584 gate_list E*N float        (131072)
  //   262656 xn bf16   N*D              (8388608)
  //   8651264  wT bf16 (w1T then w2T)   (67108864)
  //   75760128 h bf16  (N*K+128)*H      (68157440)  -> end 143917568
  int*   counts = (int*)(ws + 0);
  float* psum   = (float*)(ws + 64);
  int*   offs   = (int*)(ws + 128);
  int*   tok    = (int*)(ws + 512);
  float* gate   = (float*)(ws + 131584);
  unsigned short* xnbf = (unsigned short*)(ws + 262656);
  unsigned short* wt   = (unsigned short*)(ws + 8651264);
  unsigned short* hbuf = (unsigned short*)(ws + 75760128);

  float* bal_out   = out + (size_t)NI * DI;
  float* probs_out = bal_out + 1;

  hipMemsetAsync(ws, 0, 512, stream);
  ln_router_k<<<NI, 256, 0, stream>>>(x, gam, bet, gw, xnbf, probs_out, counts, psum, tok, gate);
  transpose_cvt_k<<<dim3(HI / 64, DI / 64, EI), 256, 0, stream>>>(w1, wt, DI, HI);
  scan_bal_k<<<1, 1, 0, stream>>>(counts, psum, offs, bal_out);
  copy_x_k<<<(NI * DI / 4) / 256, 256, 0, stream>>>(x, out);
  ffn1_k<<<dim3(HI / 128, NI / 128, EI), 256, 0, stream>>>(xnbf, wt, b1, hbuf, tok, counts, offs);
  transpose_cvt_k<<<dim3(DI / 64, HI / 64, EI), 256, 0, stream>>>(w2, wt, HI, DI);
  ffn2_k<<<dim3(DI / 128, NI / 128, EI), 256, 0, stream>>>(hbuf, wt, b2, out, tok, gate, counts, offs);
}

// Round 2
// 729.013 us; speedup vs baseline: 1.5460x; 1.5460x over previous
//
#include <hip/hip_runtime.h>
#include <hip/hip_bf16.h>
#include <math.h>

// Problem constants
#define DI   1024
#define EI   8
#define HI   4096
#define NI   4096   // B*T

typedef __bf16 bf16x8 __attribute__((ext_vector_type(8)));
typedef float  f32x4  __attribute__((ext_vector_type(4)));

// ---------- helpers ----------
__device__ __forceinline__ unsigned short f2bf(float f) {
  union { float f; unsigned u; } c; c.f = f;
  unsigned r = c.u + 0x7FFF + ((c.u >> 16) & 1);   // RNE
  return (unsigned short)(r >> 16);
}

// async global->LDS, 16B per lane; lds base must be wave-uniform
__device__ __forceinline__ void async16(const void* g, void* l) {
  __builtin_amdgcn_global_load_lds(
      (const __attribute__((address_space(1))) void*)g,
      (__attribute__((address_space(3))) void*)l, 16, 0, 0);
}

// ---------- kernel 1: fused LayerNorm + router (wave per token, NO atomics) ----------
__global__ __launch_bounds__(256) void ln_router_k(
    const float* __restrict__ x, const float* __restrict__ gamma,
    const float* __restrict__ beta, const float* __restrict__ gw,
    unsigned short* __restrict__ xnbf, float* __restrict__ probs_out,
    int* __restrict__ pairs, float2* __restrict__ gates2)
{
  const int t = threadIdx.x, lane = t & 63, wid = t >> 6;
  const int n = blockIdx.x * 4 + wid;

  const float4* xr = (const float4*)(x + (size_t)n * DI);
  float4 v[4];
  #pragma unroll
  for (int j = 0; j < 4; j++) v[j] = xr[lane * 4 + j];

  float s = 0.f, q = 0.f;
  #pragma unroll
  for (int j = 0; j < 4; j++) {
    s += v[j].x + v[j].y + v[j].z + v[j].w;
    q += v[j].x * v[j].x + v[j].y * v[j].y + v[j].z * v[j].z + v[j].w * v[j].w;
  }
  #pragma unroll
  for (int off = 1; off < 64; off <<= 1) {
    s += __shfl_xor(s, off);
    q += __shfl_xor(q, off);
  }
  const float mu = s * (1.0f / DI);
  const float rs = rsqrtf(q * (1.0f / DI) - mu * mu + 1e-5f);

  const float4* gr = (const float4*)gamma;
  const float4* br = (const float4*)beta;
  float xl[16];
  #pragma unroll
  for (int j = 0; j < 4; j++) {
    const float4 g4 = gr[lane * 4 + j];
    const float4 b4 = br[lane * 4 + j];
    xl[4 * j + 0] = (v[j].x - mu) * rs * g4.x + b4.x;
    xl[4 * j + 1] = (v[j].y - mu) * rs * g4.y + b4.y;
    xl[4 * j + 2] = (v[j].z - mu) * rs * g4.z + b4.z;
    xl[4 * j + 3] = (v[j].w - mu) * rs * g4.w + b4.w;
  }
  // store xn as bf16, 32 B per lane
  unsigned u[8];
  #pragma unroll
  for (int j = 0; j < 8; j++)
    u[j] = (unsigned)f2bf(xl[2 * j]) | ((unsigned)f2bf(xl[2 * j + 1]) << 16);
  uint4* dst = (uint4*)(xnbf + (size_t)n * DI + lane * 16);
  uint4 d0; d0.x = u[0]; d0.y = u[1]; d0.z = u[2]; d0.w = u[3];
  uint4 d1; d1.x = u[4]; d1.y = u[5]; d1.z = u[6]; d1.w = u[7];
  dst[0] = d0; dst[1] = d1;

  // router logits (fp32)
  float p[8];
  #pragma unroll
  for (int e = 0; e < 8; e++) p[e] = 0.f;
  #pragma unroll
  for (int j = 0; j < 16; j++) {
    const float4* grow = (const float4*)(gw + (size_t)(lane * 16 + j) * EI);
    const float4 ga = grow[0], gb = grow[1];
    const float xv = xl[j];
    p[0] += xv * ga.x; p[1] += xv * ga.y; p[2] += xv * ga.z; p[3] += xv * ga.w;
    p[4] += xv * gb.x; p[5] += xv * gb.y; p[6] += xv * gb.z; p[7] += xv * gb.w;
  }
  #pragma unroll
  for (int e = 0; e < 8; e++)
    #pragma unroll
    for (int off = 1; off < 64; off <<= 1) p[e] += __shfl_xor(p[e], off);

  if (lane == 0) {
    float pm = -1e30f;
    #pragma unroll
    for (int e = 0; e < 8; e++) pm = fmaxf(pm, p[e]);
    float pr[8], ps = 0.f;
    #pragma unroll
    for (int e = 0; e < 8; e++) { pr[e] = expf(p[e] - pm); ps += pr[e]; }
    const float inv = 1.0f / ps;
    #pragma unroll
    for (int e = 0; e < 8; e++) {
      pr[e] *= inv;
      probs_out[(size_t)n * EI + e] = pr[e];
    }
    // top-2, ties -> lowest index (matches lax.top_k)
    int i0 = 0; float m0 = pr[0];
    #pragma unroll
    for (int e = 1; e < 8; e++) if (pr[e] > m0) { m0 = pr[e]; i0 = e; }
    int i1 = -1; float m1 = -1e30f;
    #pragma unroll
    for (int e = 0; e < 8; e++) if (e != i0 && pr[e] > m1) { m1 = pr[e]; i1 = e; }
    const float ssum = m0 + m1 + 1e-8f;
    pairs[n] = i0 | (i1 << 8);
    float2 g2; g2.x = m0 / ssum; g2.y = m1 / ssum;
    gates2[n] = g2;
  }
}

// ---------- kernel 2: build compact per-expert lists + balance loss (1 block) ----------
__global__ __launch_bounds__(1024) void build_lists_k(
    const int* __restrict__ pairs, const float2* __restrict__ gates2,
    const float* __restrict__ probs, int* __restrict__ counts,
    int* __restrict__ offs, int* __restrict__ tok_list,
    float* __restrict__ gate_list, float* __restrict__ out_bal)
{
  __shared__ int cnt[8];
  __shared__ int cur[8];
  __shared__ float wps[16][8];
  __shared__ float ps[8];
  const int t = threadIdx.x, lane = t & 63, wid = t >> 6;
  if (t < 8) cnt[t] = 0;
  __syncthreads();

  float acc[8];
  #pragma unroll
  for (int e = 0; e < 8; e++) acc[e] = 0.f;
  for (int n = t; n < NI; n += 1024) {
    const int pr = pairs[n];
    atomicAdd(&cnt[pr & 255], 1);
    atomicAdd(&cnt[pr >> 8], 1);
    const float4* prow = (const float4*)(probs + (size_t)n * EI);
    const float4 a = prow[0], b = prow[1];
    acc[0] += a.x; acc[1] += a.y; acc[2] += a.z; acc[3] += a.w;
    acc[4] += b.x; acc[5] += b.y; acc[6] += b.z; acc[7] += b.w;
  }
  #pragma unroll
  for (int e = 0; e < 8; e++)
    #pragma unroll
    for (int off = 1; off < 64; off <<= 1) acc[e] += __shfl_xor(acc[e], off);
  if (lane == 0)
    #pragma unroll
    for (int e = 0; e < 8; e++) wps[wid][e] = acc[e];
  __syncthreads();
  if (t < 8) {
    float sm = 0.f;
    for (int w = 0; w < 16; w++) sm += wps[w][t];
    ps[t] = sm;
  }
  __syncthreads();
  if (t == 0) {
    int off = 0; float bl = 0.f;
    for (int e = 0; e < 8; e++) {
      offs[e] = off; cur[e] = off; counts[e] = cnt[e];
      bl += (float)cnt[e] * ps[e];
      off += cnt[e];
    }
    *out_bal = 0.01f * 8.0f * bl / ((float)NI * (float)NI);
  }
  __syncthreads();
  for (int n = t; n < NI; n += 1024) {
    const int pr = pairs[n];
    const float2 g = gates2[n];
    const int p0 = atomicAdd(&cur[pr & 255], 1);
    tok_list[p0] = n; gate_list[p0] = g.x;
    const int p1 = atomicAdd(&cur[pr >> 8], 1);
    tok_list[p1] = n; gate_list[p1] = g.y;
  }
}

// ---------- kernel 3: transpose fp32 (R,C) -> bf16 (C,R), per expert in z ----------
__global__ __launch_bounds__(256) void transpose_cvt_k(
    const float* __restrict__ in, unsigned short* __restrict__ out, int R, int C)
{
  __shared__ float tile[64][65];
  const size_t eoff = (size_t)blockIdx.z * (size_t)R * (size_t)C;
  const int c0 = blockIdx.x * 64, r0 = blockIdx.y * 64;
  const int tx = threadIdx.x & 63, ty = threadIdx.x >> 6;
  #pragma unroll
  for (int ii = 0; ii < 16; ii++) {
    int i = ty + ii * 4;
    tile[i][tx] = in[eoff + (size_t)(r0 + i) * C + (c0 + tx)];
  }
  __syncthreads();
  #pragma unroll
  for (int ii = 0; ii < 16; ii++) {
    int i = ty + ii * 4;
    out[eoff + (size_t)(c0 + i) * R + (r0 + tx)] = f2bf(tile[tx][i]);
  }
}

// ---------- kernel 4: residual init out = x ----------
__global__ __launch_bounds__(256) void copy_x_k(const float* __restrict__ x, float* __restrict__ out)
{
  const size_t i = (size_t)blockIdx.x * 256 + threadIdx.x;
  ((float4*)out)[i] = ((const float4*)x)[i];
}

// ---------- kernel 5: grouped GEMM1 + bias + GELU -> h (bf16) ----------
// C[m][n] over m = expert tokens (gathered), n = H cols. K = D.
__global__ __launch_bounds__(256) void ffn1_k(
    const unsigned short* __restrict__ xnbf, const unsigned short* __restrict__ w1t,
    const float* __restrict__ b1, unsigned short* __restrict__ hbuf,
    const int* __restrict__ tok_list, const int* __restrict__ counts,
    const int* __restrict__ offsets)
{
  const int e = blockIdx.z;
  const int cnt = counts[e];
  const int mt = blockIdx.y;
  if (mt * 128 >= cnt) return;
  const int n0 = blockIdx.x * 128;
  const int t = threadIdx.x, lane = t & 63, w = t >> 6;
  const int wm = w & 1, wn = w >> 1;
  __shared__ __align__(16) unsigned short As[128 * 64];  // [m][k], no pad (global_load_lds)
  __shared__ __align__(16) unsigned short Bs[128 * 64];  // [n][k]

  const int sub = lane >> 3, kc = (lane & 7) * 8;
  const int eoff = offsets[e];
  const unsigned short* baseA[4];
  const unsigned short* baseB[4];
  #pragma unroll
  for (int r = 0; r < 4; r++) {
    int row = (w << 5) + r * 8 + sub;
    int idx = mt * 128 + row; if (idx > cnt - 1) idx = cnt - 1;  // clamp (dup, unused)
    int tok = tok_list[eoff + idx];
    baseA[r] = xnbf + (size_t)tok * DI + kc;
    baseB[r] = w1t + (size_t)e * HI * DI + (size_t)(n0 + row) * DI + kc;
  }

  f32x4 acc[4][4];
  const f32x4 zz = {0.f, 0.f, 0.f, 0.f};
  #pragma unroll
  for (int i = 0; i < 4; i++)
    #pragma unroll
    for (int j = 0; j < 4; j++) acc[i][j] = zz;

  const int mrow = (wm << 6) + (lane & 15);
  const int nrow = (wn << 6) + (lane & 15);
  const int kq = (lane >> 4) * 8;

  for (int k0 = 0; k0 < DI; k0 += 64) {
    __syncthreads();
    #pragma unroll
    for (int r = 0; r < 4; r++) {
      async16(baseA[r] + k0, &As[((w << 5) + r * 8) * 64]);
      async16(baseB[r] + k0, &Bs[((w << 5) + r * 8) * 64]);
    }
    __syncthreads();
    #pragma unroll
    for (int kk = 0; kk < 2; kk++) {
      bf16x8 af[4], bfr[4];
      #pragma unroll
      for (int mi = 0; mi < 4; mi++)
        af[mi] = *(const bf16x8*)&As[(mrow + mi * 16) * 64 + kk * 32 + kq];
      #pragma unroll
      for (int ni = 0; ni < 4; ni++)
        bfr[ni] = *(const bf16x8*)&Bs[(nrow + ni * 16) * 64 + kk * 32 + kq];
      #pragma unroll
      for (int mi = 0; mi < 4; mi++)
        #pragma unroll
        for (int ni = 0; ni < 4; ni++)
          acc[mi][ni] = __builtin_amdgcn_mfma_f32_16x16x32_bf16(af[mi], bfr[ni], acc[mi][ni], 0, 0, 0);
    }
  }

  // epilogue: bias + exact GELU, store bf16 h (guarded rows)
  const int hb = eoff + mt * 128;
  #pragma unroll
  for (int ni = 0; ni < 4; ni++) {
    const int col = n0 + (wn << 6) + ni * 16 + (lane & 15);
    const float bias = b1[e * HI + col];
    #pragma unroll
    for (int mi = 0; mi < 4; mi++) {
      #pragma unroll
      for (int rg = 0; rg < 4; rg++) {
        const int rowl = (wm << 6) + mi * 16 + ((lane >> 4) << 2) + rg;
        if (mt * 128 + rowl < cnt) {
          float vv = acc[mi][ni][rg] + bias;
          vv = 0.5f * vv * (1.0f + erff(vv * 0.70710678118f));
          hbuf[(size_t)(hb + rowl) * HI + col] = f2bf(vv);
        }
      }
    }
  }
}

// ---------- kernel 6: grouped GEMM2 + bias, gate-scaled scatter-add -> out ----------
// C[m][n] over m = expert rows of h (compact), n = D cols. K = H.
__global__ __launch_bounds__(256) void ffn2_k(
    const unsigned short* __restrict__ hbuf, const unsigned short* __restrict__ w2t,
    const float* __restrict__ b2, float* __restrict__ out,
    const int* __restrict__ tok_list, const float* __restrict__ gate_list,
    const int* __restrict__ counts, const int* __restrict__ offsets)
{
  const int e = blockIdx.z;
  const int cnt = counts[e];
  const int mt = blockIdx.y;
  if (mt * 128 >= cnt) return;
  const int n0 = blockIdx.x * 128;
  const int t = threadIdx.x, lane = t & 63, w = t >> 6;
  const int wm = w & 1, wn = w >> 1;
  __shared__ __align__(16) unsigned short As[128 * 64];
  __shared__ __align__(16) unsigned short Bs[128 * 64];

  const int sub = lane >> 3, kc = (lane & 7) * 8;
  const int eoff = offsets[e];
  const int hb = eoff + mt * 128;
  const unsigned short* baseA[4];
  const unsigned short* baseB[4];
  #pragma unroll
  for (int r = 0; r < 4; r++) {
    int row = (w << 5) + r * 8 + sub;
    baseA[r] = hbuf + (size_t)(hb + row) * HI + kc;     // h padded by 128 rows
    baseB[r] = w2t + (size_t)e * DI * HI + (size_t)(n0 + row) * HI + kc;
  }

  f32x4 acc[4][4];
  const f32x4 zz = {0.f, 0.f, 0.f, 0.f};
  #pragma unroll
  for (int i = 0; i < 4; i++)
    #pragma unroll
    for (int j = 0; j < 4; j++) acc[i][j] = zz;

  const int mrow = (wm << 6) + (lane & 15);
  const int nrow = (wn << 6) + (lane & 15);
  const int kq = (lane >> 4) * 8;

  for (int k0 = 0; k0 < HI; k0 += 64) {
    __syncthreads();
    #pragma unroll
    for (int r = 0; r < 4; r++) {
      async16(baseA[r] + k0, &As[((w << 5) + r * 8) * 64]);
      async16(baseB[r] + k0, &Bs[((w << 5) + r * 8) * 64]);
    }
    __syncthreads();
    #pragma unroll
    for (int kk = 0; kk < 2; kk++) {
      bf16x8 af[4], bfr[4];
      #pragma unroll
      for (int mi = 0; mi < 4; mi++)
        af[mi] = *(const bf16x8*)&As[(mrow + mi * 16) * 64 + kk * 32 + kq];
      #pragma unroll
      for (int ni = 0; ni < 4; ni++)
        bfr[ni] = *(const bf16x8*)&Bs[(nrow + ni * 16) * 64 + kk * 32 + kq];
      #pragma unroll
      for (int mi = 0; mi < 4; mi++)
        #pragma unroll
        for (int ni = 0; ni < 4; ni++)
          acc[mi][ni] = __builtin_amdgcn_mfma_f32_16x16x32_bf16(af[mi], bfr[ni], acc[mi][ni], 0, 0, 0);
    }
  }

  // epilogue: (acc + b2) * gate, atomic scatter onto residual-initialized out
  float bias[4];
  #pragma unroll
  for (int ni = 0; ni < 4; ni++)
    bias[ni] = b2[e * DI + n0 + (wn << 6) + ni * 16 + (lane & 15)];
  #pragma unroll
  for (int mi = 0; mi < 4; mi++) {
    #pragma unroll
    for (int rg = 0; rg < 4; rg++) {
      const int rowl = (wm << 6) + mi * 16 + ((lane >> 4) << 2) + rg;
      const int gidx = mt * 128 + rowl;
      if (gidx < cnt) {
        const int tok = tok_list[eoff + gidx];
        const float gte = gate_list[eoff + gidx];
        float* orow = out + (size_t)tok * DI;
        #pragma unroll
        for (int ni = 0; ni < 4; ni++) {
          const int col = n0 + (wn << 6) + ni * 16 + (lane & 15);
          atomicAdd(orow + col, (acc[mi][ni][rg] + bias[ni]) * gte);
        }
      }
    }
  }
}

// ---------- launch ----------
extern "C" void kernel_launch(void* const* d_in, const int* in_sizes, int n_in,
                              void* d_out, int out_size, void* d_ws, size_t ws_size,
                              hipStream_t stream)
{
  const float* x   = (const float*)d_in[0];
  const float* gam = (const float*)d_in[1];
  const float* bet = (const float*)d_in[2];
  const float* gw  = (const float*)d_in[3];
  const float* w1  = (const float*)d_in[4];
  const float* b1  = (const float*)d_in[5];
  const float* w2  = (const float*)d_in[6];
  const float* b2  = (const float*)d_in[7];
  float* out = (float*)d_out;

  char* ws = (char*)d_ws;
  // ws layout (bytes):
  //   0        counts[8] (int)
  //   64       offs[8] (int)
  //   1024     pairs    N int            (16384)
  //   20480    gates2   N float2         (32768)
  //   57344    tok_list 2N int           (32768)
  //   90112    gate_list 2N float        (32768)
  //   262656   xn bf16  N*D              (8388608)
  //   8651264  wT bf16  (w1T then w2T)   (67108864)
  //   75760128 h bf16   (N*K+128)*H      (68157440)  -> end 143917568
  int*    counts = (int*)(ws + 0);
  int*    offs   = (int*)(ws + 64);
  int*    pairs  = (int*)(ws + 1024);
  float2* gates2 = (float2*)(ws + 20480);
  int*    tok    = (int*)(ws + 57344);
  float*  gate   = (float*)(ws + 90112);
  unsigned short* xnbf = (unsigned short*)(ws + 262656);
  unsigned short* wt   = (unsigned short*)(ws + 8651264);
  unsigned short* hbuf = (unsigned short*)(ws + 75760128);

  float* bal_out   = out + (size_t)NI * DI;
  float* probs_out = bal_out + 1;

  ln_router_k<<<NI / 4, 256, 0, stream>>>(x, gam, bet, gw, xnbf, probs_out, pairs, gates2);
  build_lists_k<<<1, 1024, 0, stream>>>(pairs, gates2, probs_out, counts, offs, tok, gate, bal_out);
  transpose_cvt_k<<<dim3(HI / 64, DI / 64, EI), 256, 0, stream>>>(w1, wt, DI, HI);
  copy_x_k<<<(NI * DI / 4) / 256, 256, 0, stream>>>(x, out);
  ffn1_k<<<dim3(HI / 128, NI / 128, EI), 256, 0, stream>>>(xnbf, wt, b1, hbuf, tok, counts, offs);
  transpose_cvt_k<<<dim3(DI / 64, HI / 64, EI), 256, 0, stream>>>(w2, wt, HI, DI);
  ffn2_k<<<dim3(DI / 128, NI / 128, EI), 256, 0, stream>>>(hbuf, wt, b2, out, tok, gate, counts, offs);
}

// Round 3
// 659.926 us; speedup vs baseline: 1.7078x; 1.1047x over previous
//
#include <hip/hip_runtime.h>
#include <hip/hip_bf16.h>
#include <math.h>

// Problem constants
#define DI   1024
#define EI   8
#define HI   4096
#define NI   4096   // B*T

typedef __bf16 bf16x8 __attribute__((ext_vector_type(8)));
typedef float  f32x4  __attribute__((ext_vector_type(4)));

// ---------- helpers ----------
__device__ __forceinline__ unsigned short f2bf(float f) {
  union { float f; unsigned u; } c; c.f = f;
  unsigned r = c.u + 0x7FFF + ((c.u >> 16) & 1);   // RNE
  return (unsigned short)(r >> 16);
}

// async global->LDS, 16B per lane; lds base must be wave-uniform
__device__ __forceinline__ void async16(const void* g, void* l) {
  __builtin_amdgcn_global_load_lds(
      (const __attribute__((address_space(1))) void*)g,
      (__attribute__((address_space(3))) void*)l, 16, 0, 0);
}

// ---------- kernel 1: fused LayerNorm + router (wave per token, NO atomics) ----------
__global__ __launch_bounds__(256) void ln_router_k(
    const float* __restrict__ x, const float* __restrict__ gamma,
    const float* __restrict__ beta, const float* __restrict__ gw,
    unsigned short* __restrict__ xnbf, float* __restrict__ probs_out,
    int* __restrict__ pairs, float2* __restrict__ gates2)
{
  const int t = threadIdx.x, lane = t & 63, wid = t >> 6;
  const int n = blockIdx.x * 4 + wid;

  const float4* xr = (const float4*)(x + (size_t)n * DI);
  float4 v[4];
  #pragma unroll
  for (int j = 0; j < 4; j++) v[j] = xr[lane * 4 + j];

  float s = 0.f, q = 0.f;
  #pragma unroll
  for (int j = 0; j < 4; j++) {
    s += v[j].x + v[j].y + v[j].z + v[j].w;
    q += v[j].x * v[j].x + v[j].y * v[j].y + v[j].z * v[j].z + v[j].w * v[j].w;
  }
  #pragma unroll
  for (int off = 1; off < 64; off <<= 1) {
    s += __shfl_xor(s, off);
    q += __shfl_xor(q, off);
  }
  const float mu = s * (1.0f / DI);
  const float rs = rsqrtf(q * (1.0f / DI) - mu * mu + 1e-5f);

  const float4* gr = (const float4*)gamma;
  const float4* br = (const float4*)beta;
  float xl[16];
  #pragma unroll
  for (int j = 0; j < 4; j++) {
    const float4 g4 = gr[lane * 4 + j];
    const float4 b4 = br[lane * 4 + j];
    xl[4 * j + 0] = (v[j].x - mu) * rs * g4.x + b4.x;
    xl[4 * j + 1] = (v[j].y - mu) * rs * g4.y + b4.y;
    xl[4 * j + 2] = (v[j].z - mu) * rs * g4.z + b4.z;
    xl[4 * j + 3] = (v[j].w - mu) * rs * g4.w + b4.w;
  }
  // store xn as bf16, 32 B per lane
  unsigned u[8];
  #pragma unroll
  for (int j = 0; j < 8; j++)
    u[j] = (unsigned)f2bf(xl[2 * j]) | ((unsigned)f2bf(xl[2 * j + 1]) << 16);
  uint4* dst = (uint4*)(xnbf + (size_t)n * DI + lane * 16);
  uint4 d0; d0.x = u[0]; d0.y = u[1]; d0.z = u[2]; d0.w = u[3];
  uint4 d1; d1.x = u[4]; d1.y = u[5]; d1.z = u[6]; d1.w = u[7];
  dst[0] = d0; dst[1] = d1;

  // router logits (fp32)
  float p[8];
  #pragma unroll
  for (int e = 0; e < 8; e++) p[e] = 0.f;
  #pragma unroll
  for (int j = 0; j < 16; j++) {
    const float4* grow = (const float4*)(gw + (size_t)(lane * 16 + j) * EI);
    const float4 ga = grow[0], gb = grow[1];
    const float xv = xl[j];
    p[0] += xv * ga.x; p[1] += xv * ga.y; p[2] += xv * ga.z; p[3] += xv * ga.w;
    p[4] += xv * gb.x; p[5] += xv * gb.y; p[6] += xv * gb.z; p[7] += xv * gb.w;
  }
  #pragma unroll
  for (int e = 0; e < 8; e++)
    #pragma unroll
    for (int off = 1; off < 64; off <<= 1) p[e] += __shfl_xor(p[e], off);

  if (lane == 0) {
    float pm = -1e30f;
    #pragma unroll
    for (int e = 0; e < 8; e++) pm = fmaxf(pm, p[e]);
    float pr[8], ps = 0.f;
    #pragma unroll
    for (int e = 0; e < 8; e++) { pr[e] = expf(p[e] - pm); ps += pr[e]; }
    const float inv = 1.0f / ps;
    #pragma unroll
    for (int e = 0; e < 8; e++) {
      pr[e] *= inv;
      probs_out[(size_t)n * EI + e] = pr[e];
    }
    // top-2, ties -> lowest index (matches lax.top_k)
    int i0 = 0; float m0 = pr[0];
    #pragma unroll
    for (int e = 1; e < 8; e++) if (pr[e] > m0) { m0 = pr[e]; i0 = e; }
    int i1 = -1; float m1 = -1e30f;
    #pragma unroll
    for (int e = 0; e < 8; e++) if (e != i0 && pr[e] > m1) { m1 = pr[e]; i1 = e; }
    const float ssum = m0 + m1 + 1e-8f;
    pairs[n] = i0 | (i1 << 8);
    float2 g2; g2.x = m0 / ssum; g2.y = m1 / ssum;
    gates2[n] = g2;
  }
}

// ---------- kernel 2: build compact per-expert lists + balance loss (1 block) ----------
__global__ __launch_bounds__(1024) void build_lists_k(
    const int* __restrict__ pairs, const float2* __restrict__ gates2,
    const float* __restrict__ probs, int* __restrict__ counts,
    int* __restrict__ offs, int* __restrict__ tok_list,
    float* __restrict__ gate_list, int2* __restrict__ ipos,
    float* __restrict__ out_bal)
{
  __shared__ int cnt[8];
  __shared__ int cur[8];
  __shared__ float wps[16][8];
  __shared__ float ps[8];
  const int t = threadIdx.x, lane = t & 63, wid = t >> 6;
  if (t < 8) cnt[t] = 0;
  __syncthreads();

  float acc[8];
  #pragma unroll
  for (int e = 0; e < 8; e++) acc[e] = 0.f;
  for (int n = t; n < NI; n += 1024) {
    const int pr = pairs[n];
    atomicAdd(&cnt[pr & 255], 1);
    atomicAdd(&cnt[pr >> 8], 1);
    const float4* prow = (const float4*)(probs + (size_t)n * EI);
    const float4 a = prow[0], b = prow[1];
    acc[0] += a.x; acc[1] += a.y; acc[2] += a.z; acc[3] += a.w;
    acc[4] += b.x; acc[5] += b.y; acc[6] += b.z; acc[7] += b.w;
  }
  #pragma unroll
  for (int e = 0; e < 8; e++)
    #pragma unroll
    for (int off = 1; off < 64; off <<= 1) acc[e] += __shfl_xor(acc[e], off);
  if (lane == 0)
    #pragma unroll
    for (int e = 0; e < 8; e++) wps[wid][e] = acc[e];
  __syncthreads();
  if (t < 8) {
    float sm = 0.f;
    for (int w = 0; w < 16; w++) sm += wps[w][t];
    ps[t] = sm;
  }
  __syncthreads();
  if (t == 0) {
    int off = 0; float bl = 0.f;
    for (int e = 0; e < 8; e++) {
      offs[e] = off; cur[e] = off; counts[e] = cnt[e];
      bl += (float)cnt[e] * ps[e];
      off += cnt[e];
    }
    *out_bal = 0.01f * 8.0f * bl / ((float)NI * (float)NI);
  }
  __syncthreads();
  for (int n = t; n < NI; n += 1024) {
    const int pr = pairs[n];
    const float2 g = gates2[n];
    const int p0 = atomicAdd(&cur[pr & 255], 1);
    tok_list[p0] = n; gate_list[p0] = g.x;
    const int p1 = atomicAdd(&cur[pr >> 8], 1);
    tok_list[p1] = n; gate_list[p1] = g.y;
    int2 ip; ip.x = p0; ip.y = p1;
    ipos[n] = ip;
  }
}

// ---------- kernel 3: transpose fp32 (R,C) -> bf16 (C,R), per expert in z ----------
// vectorized: float4 loads, ushort8 (16B) stores
__global__ __launch_bounds__(256) void transpose_cvt_k(
    const float* __restrict__ in, unsigned short* __restrict__ out, int R, int C)
{
  __shared__ float tile[64][65];
  const size_t eoff = (size_t)blockIdx.z * (size_t)R * (size_t)C;
  const int c0 = blockIdx.x * 64, r0 = blockIdx.y * 64;
  const int t = threadIdx.x;
  {
    const int col = (t & 15) * 4;
    #pragma unroll
    for (int ii = 0; ii < 4; ii++) {
      const int row = (t >> 4) + ii * 16;
      const float4 v = *(const float4*)(in + eoff + (size_t)(r0 + row) * C + c0 + col);
      tile[row][col + 0] = v.x; tile[row][col + 1] = v.y;
      tile[row][col + 2] = v.z; tile[row][col + 3] = v.w;
    }
  }
  __syncthreads();
  {
    const int grp = t & 7;
    #pragma unroll
    for (int jj = 0; jj < 2; jj++) {
      const int orow = (t >> 3) + jj * 32;
      unsigned short vs[8];
      #pragma unroll
      for (int u = 0; u < 8; u++) vs[u] = f2bf(tile[grp * 8 + u][orow]);
      uint4 pk;
      pk.x = (unsigned)vs[0] | ((unsigned)vs[1] << 16);
      pk.y = (unsigned)vs[2] | ((unsigned)vs[3] << 16);
      pk.z = (unsigned)vs[4] | ((unsigned)vs[5] << 16);
      pk.w = (unsigned)vs[6] | ((unsigned)vs[7] << 16);
      *(uint4*)(out + eoff + (size_t)(c0 + orow) * R + r0 + grp * 8) = pk;
    }
  }
}

// ---------- kernel 4: residual init out = x (atomic fallback path only) ----------
__global__ __launch_bounds__(256) void copy_x_k(const float* __restrict__ x, float* __restrict__ out)
{
  const size_t i = (size_t)blockIdx.x * 256 + threadIdx.x;
  ((float4*)out)[i] = ((const float4*)x)[i];
}

// ---------- kernel 5: grouped GEMM1 + bias + GELU -> h (bf16), XOR-swizzled LDS ----------
__global__ __launch_bounds__(256) void ffn1_k(
    const unsigned short* __restrict__ xnbf, const unsigned short* __restrict__ w1t,
    const float* __restrict__ b1, unsigned short* __restrict__ hbuf,
    const int* __restrict__ tok_list, const int* __restrict__ counts,
    const int* __restrict__ offsets)
{
  const int e = blockIdx.z;
  const int cnt = counts[e];
  const int mt = blockIdx.y;
  if (mt * 128 >= cnt) return;
  const int n0 = blockIdx.x * 128;
  const int t = threadIdx.x, lane = t & 63, w = t >> 6;
  const int wm = w & 1, wn = w >> 1;
  __shared__ __align__(16) unsigned short As[128 * 64];  // [m][k], XOR(row&7) col-group swizzle
  __shared__ __align__(16) unsigned short Bs[128 * 64];  // [n][k]

  const int sub = lane >> 3;
  const int kc = (((lane & 7) ^ sub) * 8);   // swizzled global column group
  const int eoff = offsets[e];
  const unsigned short* baseA[4];
  const unsigned short* baseB[4];
  #pragma unroll
  for (int r = 0; r < 4; r++) {
    int row = (w << 5) + r * 8 + sub;
    int idx = mt * 128 + row; if (idx > cnt - 1) idx = cnt - 1;  // clamp (dup, unused)
    int tok = tok_list[eoff + idx];
    baseA[r] = xnbf + (size_t)tok * DI + kc;
    baseB[r] = w1t + (size_t)e * HI * DI + (size_t)(n0 + row) * DI + kc;
  }

  f32x4 acc[4][4];
  const f32x4 zz = {0.f, 0.f, 0.f, 0.f};
  #pragma unroll
  for (int i = 0; i < 4; i++)
    #pragma unroll
    for (int j = 0; j < 4; j++) acc[i][j] = zz;

  const int mrow = (wm << 6) + (lane & 15);
  const int nrow = (wn << 6) + (lane & 15);
  // swizzled k-offset (shorts) for fragment reads; row&7 == lane&7 for all frag rows
  const int ksw[2] = { (((lane >> 4) ^ (lane & 7)) * 8),
                       ((((lane >> 4) + 4) ^ (lane & 7)) * 8) };

  for (int k0 = 0; k0 < DI; k0 += 64) {
    __syncthreads();
    #pragma unroll
    for (int r = 0; r < 4; r++) {
      async16(baseA[r] + k0, &As[((w << 5) + r * 8) * 64]);
      async16(baseB[r] + k0, &Bs[((w << 5) + r * 8) * 64]);
    }
    __syncthreads();
    #pragma unroll
    for (int kk = 0; kk < 2; kk++) {
      const int ko = ksw[kk];
      bf16x8 af[4], bfr[4];
      #pragma unroll
      for (int mi = 0; mi < 4; mi++)
        af[mi] = *(const bf16x8*)&As[(mrow + mi * 16) * 64 + ko];
      #pragma unroll
      for (int ni = 0; ni < 4; ni++)
        bfr[ni] = *(const bf16x8*)&Bs[(nrow + ni * 16) * 64 + ko];
      #pragma unroll
      for (int mi = 0; mi < 4; mi++)
        #pragma unroll
        for (int ni = 0; ni < 4; ni++)
          acc[mi][ni] = __builtin_amdgcn_mfma_f32_16x16x32_bf16(af[mi], bfr[ni], acc[mi][ni], 0, 0, 0);
    }
  }

  // epilogue: bias + exact GELU, store bf16 h (guarded rows)
  const int hb = eoff + mt * 128;
  #pragma unroll
  for (int ni = 0; ni < 4; ni++) {
    const int col = n0 + (wn << 6) + ni * 16 + (lane & 15);
    const float bias = b1[e * HI + col];
    #pragma unroll
    for (int mi = 0; mi < 4; mi++) {
      #pragma unroll
      for (int rg = 0; rg < 4; rg++) {
        const int rowl = (wm << 6) + mi * 16 + ((lane >> 4) << 2) + rg;
        if (mt * 128 + rowl < cnt) {
          float vv = acc[mi][ni][rg] + bias;
          vv = 0.5f * vv * (1.0f + erff(vv * 0.70710678118f));
          hbuf[(size_t)(hb + rowl) * HI + col] = f2bf(vv);
        }
      }
    }
  }
}

// ---------- kernel 6: grouped GEMM2 + bias -> eo (or atomic scatter), XOR-swizzled LDS ----------
__global__ __launch_bounds__(256) void ffn2_k(
    const unsigned short* __restrict__ hbuf, const unsigned short* __restrict__ w2t,
    const float* __restrict__ b2, float* __restrict__ out,
    const int* __restrict__ tok_list, const float* __restrict__ gate_list,
    const int* __restrict__ counts, const int* __restrict__ offsets,
    float* __restrict__ eo)
{
  const int e = blockIdx.z;
  const int cnt = counts[e];
  const int mt = blockIdx.y;
  if (mt * 128 >= cnt) return;
  const int n0 = blockIdx.x * 128;
  const int t = threadIdx.x, lane = t & 63, w = t >> 6;
  const int wm = w & 1, wn = w >> 1;
  __shared__ __align__(16) unsigned short As[128 * 64];
  __shared__ __align__(16) unsigned short Bs[128 * 64];

  const int sub = lane >> 3;
  const int kc = (((lane & 7) ^ sub) * 8);
  const int eoff = offsets[e];
  const int hb = eoff + mt * 128;
  const unsigned short* baseA[4];
  const unsigned short* baseB[4];
  #pragma unroll
  for (int r = 0; r < 4; r++) {
    int row = (w << 5) + r * 8 + sub;
    baseA[r] = hbuf + (size_t)(hb + row) * HI + kc;     // h padded by 128 rows
    baseB[r] = w2t + (size_t)e * DI * HI + (size_t)(n0 + row) * HI + kc;
  }

  f32x4 acc[4][4];
  const f32x4 zz = {0.f, 0.f, 0.f, 0.f};
  #pragma unroll
  for (int i = 0; i < 4; i++)
    #pragma unroll
    for (int j = 0; j < 4; j++) acc[i][j] = zz;

  const int mrow = (wm << 6) + (lane & 15);
  const int nrow = (wn << 6) + (lane & 15);
  const int ksw[2] = { (((lane >> 4) ^ (lane & 7)) * 8),
                       ((((lane >> 4) + 4) ^ (lane & 7)) * 8) };

  for (int k0 = 0; k0 < HI; k0 += 64) {
    __syncthreads();
    #pragma unroll
    for (int r = 0; r < 4; r++) {
      async16(baseA[r] + k0, &As[((w << 5) + r * 8) * 64]);
      async16(baseB[r] + k0, &Bs[((w << 5) + r * 8) * 64]);
    }
    __syncthreads();
    #pragma unroll
    for (int kk = 0; kk < 2; kk++) {
      const int ko = ksw[kk];
      bf16x8 af[4], bfr[4];
      #pragma unroll
      for (int mi = 0; mi < 4; mi++)
        af[mi] = *(const bf16x8*)&As[(mrow + mi * 16) * 64 + ko];
      #pragma unroll
      for (int ni = 0; ni < 4; ni++)
        bfr[ni] = *(const bf16x8*)&Bs[(nrow + ni * 16) * 64 + ko];
      #pragma unroll
      for (int mi = 0; mi < 4; mi++)
        #pragma unroll
        for (int ni = 0; ni < 4; ni++)
          acc[mi][ni] = __builtin_amdgcn_mfma_f32_16x16x32_bf16(af[mi], bfr[ni], acc[mi][ni], 0, 0, 0);
    }
  }

  float bias[4];
  #pragma unroll
  for (int ni = 0; ni < 4; ni++)
    bias[ni] = b2[e * DI + n0 + (wn << 6) + ni * 16 + (lane & 15)];

  if (eo) {
    // write raw expert_out rows (compact layout), no atomics; combine_k finishes
    #pragma unroll
    for (int mi = 0; mi < 4; mi++) {
      #pragma unroll
      for (int rg = 0; rg < 4; rg++) {
        const int rowl = (wm << 6) + mi * 16 + ((lane >> 4) << 2) + rg;
        const int gidx = mt * 128 + rowl;
        if (gidx < cnt) {
          float* erow = eo + (size_t)(hb + rowl) * DI;
          #pragma unroll
          for (int ni = 0; ni < 4; ni++) {
            const int col = n0 + (wn << 6) + ni * 16 + (lane & 15);
            erow[col] = acc[mi][ni][rg] + bias[ni];
          }
        }
      }
    }
  } else {
    // fallback: (acc + b2) * gate, atomic scatter onto residual-initialized out
    #pragma unroll
    for (int mi = 0; mi < 4; mi++) {
      #pragma unroll
      for (int rg = 0; rg < 4; rg++) {
        const int rowl = (wm << 6) + mi * 16 + ((lane >> 4) << 2) + rg;
        const int gidx = mt * 128 + rowl;
        if (gidx < cnt) {
          const int tok = tok_list[eoff + gidx];
          const float gte = gate_list[eoff + gidx];
          float* orow = out + (size_t)tok * DI;
          #pragma unroll
          for (int ni = 0; ni < 4; ni++) {
            const int col = n0 + (wn << 6) + ni * 16 + (lane & 15);
            atomicAdd(orow + col, (acc[mi][ni][rg] + bias[ni]) * gte);
          }
        }
      }
    }
  }
}

// ---------- kernel 7: out = x + g0*eo[p0] + g1*eo[p1] ----------
__global__ __launch_bounds__(256) void combine_k(
    const float* __restrict__ x, const float* __restrict__ eo,
    const int2* __restrict__ ipos, const float2* __restrict__ gates2,
    float* __restrict__ out)
{
  const int n = blockIdx.x, t = threadIdx.x;
  const int2 pp = ipos[n];
  const float2 gg = gates2[n];
  const float4 a = ((const float4*)(x  + (size_t)n    * DI))[t];
  const float4 b = ((const float4*)(eo + (size_t)pp.x * DI))[t];
  const float4 c = ((const float4*)(eo + (size_t)pp.y * DI))[t];
  float4 r;
  r.x = a.x + gg.x * b.x + gg.y * c.x;
  r.y = a.y + gg.x * b.y + gg.y * c.y;
  r.z = a.z + gg.x * b.z + gg.y * c.z;
  r.w = a.w + gg.x * b.w + gg.y * c.w;
  ((float4*)(out + (size_t)n * DI))[t] = r;
}

// ---------- launch ----------
extern "C" void kernel_launch(void* const* d_in, const int* in_sizes, int n_in,
                              void* d_out, int out_size, void* d_ws, size_t ws_size,
                              hipStream_t stream)
{
  const float* x   = (const float*)d_in[0];
  const float* gam = (const float*)d_in[1];
  const float* bet = (const float*)d_in[2];
  const float* gw  = (const float*)d_in[3];
  const float* w1  = (const float*)d_in[4];
  const float* b1  = (const float*)d_in[5];
  const float* w2  = (const float*)d_in[6];
  const float* b2  = (const float*)d_in[7];
  float* out = (float*)d_out;

  char* ws = (char*)d_ws;
  // ws layout (bytes):
  //   0        counts[8] (int)
  //   64       offs[8] (int)
  //   1024     pairs    N int            (16384)
  //   20480    gates2   N float2         (32768)
  //   57344    tok_list 2N int           (32768)
  //   90112    gate_list 2N float        (32768)
  //   122880   ipos     N int2           (32768)
  //   262656   xn bf16  N*D              (8388608)
  //   8651264  wT bf16  (w1T then w2T)   (67108864)
  //   75760128 h bf16   (N*K+128)*H      (68157440)  -> 143917568
  //   143917568 eo fp32 N*K*D            (33554432)  -> 177472000 (optional)
  int*    counts = (int*)(ws + 0);
  int*    offs   = (int*)(ws + 64);
  int*    pairs  = (int*)(ws + 1024);
  float2* gates2 = (float2*)(ws + 20480);
  int*    tok    = (int*)(ws + 57344);
  float*  gate   = (float*)(ws + 90112);
  int2*   ipos   = (int2*)(ws + 122880);
  unsigned short* xnbf = (unsigned short*)(ws + 262656);
  unsigned short* wt   = (unsigned short*)(ws + 8651264);
  unsigned short* hbuf = (unsigned short*)(ws + 75760128);
  const bool use_eo = (ws_size >= 177472000ull);
  float* eo = use_eo ? (float*)(ws + 143917568) : (float*)nullptr;

  float* bal_out   = out + (size_t)NI * DI;
  float* probs_out = bal_out + 1;

  ln_router_k<<<NI / 4, 256, 0, stream>>>(x, gam, bet, gw, xnbf, probs_out, pairs, gates2);
  build_lists_k<<<1, 1024, 0, stream>>>(pairs, gates2, probs_out, counts, offs, tok, gate, ipos, bal_out);
  transpose_cvt_k<<<dim3(HI / 64, DI / 64, EI), 256, 0, stream>>>(w1, wt, DI, HI);
  if (!use_eo)
    copy_x_k<<<(NI * DI / 4) / 256, 256, 0, stream>>>(x, out);
  ffn1_k<<<dim3(HI / 128, NI / 128, EI), 256, 0, stream>>>(xnbf, wt, b1, hbuf, tok, counts, offs);
  transpose_cvt_k<<<dim3(DI / 64, HI / 64, EI), 256, 0, stream>>>(w2, wt, HI, DI);
  ffn2_k<<<dim3(DI / 128, NI / 128, EI), 256, 0, stream>>>(hbuf, wt, b2, out, tok, gate, counts, offs, eo);
  if (use_eo)
    combine_k<<<NI, 256, 0, stream>>>(x, eo, ipos, gates2, out);
}